// Round 9
// baseline (123.304 us; speedup 1.0000x reference)
//
#include <hip/hip_runtime.h>

#define B 2
#define S 2048
#define A 16
#define H 1024
#define NH 16
#define HD 64
#define KT 16   // k-rows per scores block
#define HG 8    // heads per scores block (32 KB LDS -> 4 blocks/CU)
#define CH 4    // j-chunks per head in kQW
#define QC 16   // query rows per kD block
#define KC 1024 // k columns per kD block
#define NKT (S / KT)   // 128 partial-stat tiles per (b,h)

// ---- kQW: fused masked-mean + Q projection + effective K-weights ----------
// grid = B*NH*CH = 128 blocks (unchanged from R7 / 118.9 us).
__global__ __launch_bounds__(256) void kQW(const float* __restrict__ h2,
                                           const int* __restrict__ amask,
                                           const float* __restrict__ Wq,
                                           const float* __restrict__ Wk,
                                           float* __restrict__ weff) {
    __shared__ float agg[H];
    __shared__ float qs[HD];
    int blk = blockIdx.x;
    int c = blk & (CH - 1);
    int bh = blk / CH;
    int b = bh >> 4, h = bh & 15;
    int tid = threadIdx.x;

    {
        const float4* h2b = (const float4*)(h2 + (size_t)b * A * H);
        float4 sum = make_float4(0.f, 0.f, 0.f, 0.f);
        int cnt = 0;
#pragma unroll
        for (int a = 0; a < A; a++) {
            if (amask[b * A + a]) {
                float4 v = h2b[a * (H / 4) + tid];
                sum.x += v.x; sum.y += v.y; sum.z += v.z; sum.w += v.w; cnt++;
            }
        }
        float inv = 1.0f / (float)(cnt > 0 ? cnt : 1);
        ((float4*)agg)[tid] = make_float4(sum.x * inv, sum.y * inv, sum.z * inv, sum.w * inv);
    }
    __syncthreads();

    int wave = tid >> 6, lane = tid & 63;
    const float4* ag = (const float4*)agg;
    for (int d = wave * 16; d < wave * 16 + 16; d++) {
        const float4* wr = (const float4*)(Wq + (size_t)(h * HD + d) * H);
        float acc = 0.f;
#pragma unroll
        for (int t = 0; t < 4; t++) {
            int j4 = lane + 64 * t;
            float4 a4 = ag[j4], w4 = wr[j4];
            acc += a4.x * w4.x + a4.y * w4.y + a4.z * w4.z + a4.w * w4.w;
        }
        for (int off = 32; off > 0; off >>= 1) acc += __shfl_down(acc, off);
        if (lane == 0) qs[d] = acc;
    }
    __syncthreads();

    int j = c * 256 + tid;
    float acc = 0.f;
#pragma unroll 8
    for (int d = 0; d < HD; d++) acc += qs[d] * Wk[(size_t)(h * HD + d) * H + j];
    weff[((size_t)b * NH + h) * H + j] = acc * 0.125f;  // scale = 64^-0.5
}

// ---- kB: scores + per-tile masked softmax partials ------------------------
// grid = B * NKT * 2 head-groups = 512 blocks; 32 KB LDS (4 blocks/CU).
// Score loop identical to R7; adds a tiny per-block stats tail.
__global__ __launch_bounds__(256) void kB(const float* __restrict__ h1,
                                          const float* __restrict__ weff,
                                          const int* __restrict__ smask,
                                          float* __restrict__ s,
                                          float* __restrict__ pmax,
                                          float* __restrict__ psum) {
    __shared__ float4 lw[HG * H / 4];  // 32 KB
    __shared__ float s_tile[HG][KT];
    __shared__ int mk_tile[KT];
    int blk = blockIdx.x;
    int hg = blk & 1;
    int rest = blk >> 1;
    int kt = rest % NKT;
    int b  = rest / NKT;
    const float4* wsrc = (const float4*)(weff + ((size_t)b * NH + hg * HG) * H);
    for (int i = threadIdx.x; i < HG * H / 4; i += 256) lw[i] = wsrc[i];
    if (threadIdx.x < KT) mk_tile[threadIdx.x] = smask[b * S + kt * KT + threadIdx.x];
    __syncthreads();

    int wave = threadIdx.x >> 6, lane = threadIdx.x & 63;
    for (int kl = wave; kl < KT; kl += 4) {
        int k = kt * KT + kl;
        const float4* row = (const float4*)(h1 + ((size_t)b * S + k) * H);
        float4 x[4];
#pragma unroll
        for (int t = 0; t < 4; t++) x[t] = row[lane + 64 * t];
#pragma unroll
        for (int hh = 0; hh < HG; hh++) {
            float acc = 0.f;
#pragma unroll
            for (int t = 0; t < 4; t++) {
                float4 wv = lw[hh * (H / 4) + lane + 64 * t];
                acc += wv.x * x[t].x + wv.y * x[t].y + wv.z * x[t].z + wv.w * x[t].w;
            }
            for (int off = 32; off > 0; off >>= 1) acc += __shfl_down(acc, off);
            if (lane == 0) {
                s[((size_t)b * NH + hg * HG + hh) * S + k] = acc;
                s_tile[hh][kl] = acc;
            }
        }
    }
    __syncthreads();

    // per-head masked (max, expsum) partial over this KT tile
    if (threadIdx.x < HG) {
        int hh = threadIdx.x;
        float mx = -3.4e38f;
#pragma unroll
        for (int i = 0; i < KT; i++) if (mk_tile[i]) mx = fmaxf(mx, s_tile[hh][i]);
        float sum = 0.f;
#pragma unroll
        for (int i = 0; i < KT; i++) if (mk_tile[i]) sum += expf(s_tile[hh][i] - mx);
        int idx = ((b * NH + hg * HG + hh) * NKT) + kt;
        pmax[idx] = mx;
        psum[idx] = sum;
    }
}

// ---- kD: combine partials -> stats, then head-mean weight + broadcast -----
// grid = B * (S/KC) * (S/QC) = 512 blocks.
__global__ __launch_bounds__(256) void kD(const float* __restrict__ s,
                                          const int* __restrict__ smask,
                                          const float* __restrict__ pmax,
                                          const float* __restrict__ psum,
                                          float* __restrict__ out) {
    __shared__ float wch[KC];  // 4 KB
    __shared__ float mh_s[NH], ih_s[NH];
    int blk = blockIdx.x;
    int b  = blk >> 8;                  // 256 blocks per batch
    int r  = blk & 255;
    int kc = r >> 7;                    // 0..1
    int q0 = (r & 127) * QC;
    int tid = threadIdx.x, wave = tid >> 6, lane = tid & 63;

    // combine 128 partials per head: wave w owns heads 4w..4w+3
#pragma unroll
    for (int hh = 0; hh < 4; hh++) {
        int h = wave * 4 + hh;
        int base = (b * NH + h) * NKT;
        float m1 = pmax[base + lane], m2 = pmax[base + 64 + lane];
        float mx = fmaxf(m1, m2);
        for (int off = 32; off > 0; off >>= 1) mx = fmaxf(mx, __shfl_down(mx, off));
        mx = __shfl(mx, 0);
        float sum = psum[base + lane] * expf(m1 - mx)
                  + psum[base + 64 + lane] * expf(m2 - mx);
        for (int off = 32; off > 0; off >>= 1) sum += __shfl_down(sum, off);
        if (lane == 0) { mh_s[h] = mx; ih_s[h] = 1.0f / sum; }
    }
    __syncthreads();

    float mh[NH], ih[NH];
#pragma unroll
    for (int h = 0; h < NH; h++) { mh[h] = mh_s[h]; ih[h] = ih_s[h]; }

    // compute w chunk: one float4 per thread
    {
        int k = kc * KC + tid * 4;
        int4 mk = *(const int4*)(smask + b * S + k);
        float4 val = make_float4(0.f, 0.f, 0.f, 0.f);
#pragma unroll
        for (int h = 0; h < NH; h++) {
            float4 sv = *(const float4*)(s + ((size_t)b * NH + h) * S + k);
            val.x += expf(sv.x - mh[h]) * ih[h];
            val.y += expf(sv.y - mh[h]) * ih[h];
            val.z += expf(sv.z - mh[h]) * ih[h];
            val.w += expf(sv.w - mh[h]) * ih[h];
        }
        const float inh = 1.0f / NH;
        val.x = mk.x ? val.x * inh : 0.f;
        val.y = mk.y ? val.y * inh : 0.f;
        val.z = mk.z ? val.z * inh : 0.f;
        val.w = mk.w ? val.w * inh : 0.f;
        ((float4*)wch)[tid] = val;
    }
    __syncthreads();

    // broadcast: QC rows, each row writes KC floats (256 float4)
    float4 v = ((float4*)wch)[tid];
#pragma unroll
    for (int qi = 0; qi < QC; qi++) {
        float4* dst = (float4*)(out + ((size_t)(b * S + q0 + qi)) * S + kc * KC);
        dst[tid] = v;
    }
}

extern "C" void kernel_launch(void* const* d_in, const int* in_sizes, int n_in,
                              void* d_out, int out_size, void* d_ws, size_t ws_size,
                              hipStream_t stream) {
    const float* h1    = (const float*)d_in[0];   // [B,S,H]
    const float* h2    = (const float*)d_in[1];   // [B,A,H]
    const int*   smask = (const int*)d_in[2];     // [B,S]
    const int*   amask = (const int*)d_in[3];     // [B,A]
    const float* Wq    = (const float*)d_in[4];   // [H,H]
    const float* Wk    = (const float*)d_in[5];   // [H,H]
    float* out = (float*)d_out;                   // [B,S,S]
    float* ws  = (float*)d_ws;

    float* weff = ws;            // B*NH*H = 32768 floats
    float* s    = ws + 32768;    // B*NH*S = 65536 floats
    float* pmax = ws + 98304;    // B*NH*NKT = 4096
    float* psum = ws + 102400;   // 4096

    kQW<<<B * NH * CH, 256, 0, stream>>>(h2, amask, Wq, Wk, weff);
    kB <<<B * NKT * 2, 256, 0, stream>>>(h1, weff, smask, s, pmax, psum);
    kD <<<B * (S / KC) * (S / QC), 256, 0, stream>>>(s, smask, pmax, psum, out);
}

// Round 10
// 118.481 us; speedup vs baseline: 1.0407x; 1.0407x over previous
//
#include <hip/hip_runtime.h>

#define B 2
#define S 2048
#define A 16
#define H 1024
#define NH 16
#define HD 64
#define KT 16  // k-rows per scores block (amortize 32KB staging over 2x rows vs R4)
#define HG 8   // heads per scores block (32 KB LDS -> 4 blocks/CU)
#define CH 4   // j-chunks per head in kQW
#define QC 16  // query rows per kD block
#define KC 1024 // k columns per kD block

// ---- kQW: fused masked-mean + Q projection + effective K-weights ----------
// grid = B*NH*CH = 128 blocks. Each block redundantly computes agg[b] and
// q[b,h,:] (cheap, L2-hot), then 256 weff outputs with coalesced Wk reads.
__global__ __launch_bounds__(256) void kQW(const float* __restrict__ h2,
                                           const int* __restrict__ amask,
                                           const float* __restrict__ Wq,
                                           const float* __restrict__ Wk,
                                           float* __restrict__ weff) {
    __shared__ float agg[H];
    __shared__ float qs[HD];
    int blk = blockIdx.x;
    int c = blk & (CH - 1);
    int bh = blk / CH;
    int b = bh >> 4, h = bh & 15;
    int tid = threadIdx.x;

    // masked mean over aspects: thread owns 4 contiguous columns
    {
        const float4* h2b = (const float4*)(h2 + (size_t)b * A * H);
        float4 sum = make_float4(0.f, 0.f, 0.f, 0.f);
        int cnt = 0;
#pragma unroll
        for (int a = 0; a < A; a++) {
            if (amask[b * A + a]) {
                float4 v = h2b[a * (H / 4) + tid];
                sum.x += v.x; sum.y += v.y; sum.z += v.z; sum.w += v.w; cnt++;
            }
        }
        float inv = 1.0f / (float)(cnt > 0 ? cnt : 1);
        ((float4*)agg)[tid] = make_float4(sum.x * inv, sum.y * inv, sum.z * inv, sum.w * inv);
    }
    __syncthreads();

    // q for this head: 64 wave-dots (4 waves x 16)
    int wave = tid >> 6, lane = tid & 63;
    const float4* ag = (const float4*)agg;
    for (int d = wave * 16; d < wave * 16 + 16; d++) {
        const float4* wr = (const float4*)(Wq + (size_t)(h * HD + d) * H);
        float acc = 0.f;
#pragma unroll
        for (int t = 0; t < 4; t++) {
            int j4 = lane + 64 * t;
            float4 a4 = ag[j4], w4 = wr[j4];
            acc += a4.x * w4.x + a4.y * w4.y + a4.z * w4.z + a4.w * w4.w;
        }
        for (int off = 32; off > 0; off >>= 1) acc += __shfl_down(acc, off);
        if (lane == 0) qs[d] = acc;
    }
    __syncthreads();

    // weff chunk: one thread per output column j; Wk reads coalesced
    int j = c * 256 + tid;
    float acc = 0.f;
#pragma unroll 8
    for (int d = 0; d < HD; d++) acc += qs[d] * Wk[(size_t)(h * HD + d) * H + j];
    weff[((size_t)b * NH + h) * H + j] = acc * 0.125f;  // scale = 64^-0.5
}

// ---- kB: scores s[b,h,k] = weff[b,h,:] . h1[b,k,:] ------------------------
// grid = B * (S/KT) * 2 head-groups = 512 blocks; 32 KB LDS (4 blocks/CU)
__global__ __launch_bounds__(256) void kB(const float* __restrict__ h1,
                                          const float* __restrict__ weff,
                                          float* __restrict__ s) {
    __shared__ float4 lw[HG * H / 4];  // 32 KB
    int blk = blockIdx.x;
    int hg = blk & 1;
    int rest = blk >> 1;
    int kt = rest % (S / KT);
    int b  = rest / (S / KT);
    const float4* wsrc = (const float4*)(weff + ((size_t)b * NH + hg * HG) * H);
    for (int i = threadIdx.x; i < HG * H / 4; i += 256) lw[i] = wsrc[i];
    __syncthreads();

    int wave = threadIdx.x >> 6, lane = threadIdx.x & 63;
    for (int kl = wave; kl < KT; kl += 4) {
        int k = kt * KT + kl;
        const float4* row = (const float4*)(h1 + ((size_t)b * S + k) * H);
        float4 x[4];
#pragma unroll
        for (int t = 0; t < 4; t++) x[t] = row[lane + 64 * t];
#pragma unroll
        for (int hh = 0; hh < HG; hh++) {
            float acc = 0.f;
#pragma unroll
            for (int t = 0; t < 4; t++) {
                float4 wv = lw[hh * (H / 4) + lane + 64 * t];
                acc += wv.x * x[t].x + wv.y * x[t].y + wv.z * x[t].z + wv.w * x[t].w;
            }
            for (int off = 32; off > 0; off >>= 1) acc += __shfl_down(acc, off);
            if (lane == 0) s[((size_t)b * NH + hg * HG + hh) * S + k] = acc;
        }
    }
}

// ---- kS: masked softmax stats, one block per (b,h) ------------------------
__global__ __launch_bounds__(256) void kS(const float* __restrict__ s,
                                          const int* __restrict__ smask,
                                          float* __restrict__ m,
                                          float* __restrict__ dsum) {
    __shared__ float red[4];
    int bh = blockIdx.x, b = bh >> 4;
    int tid = threadIdx.x, wave = tid >> 6, lane = tid & 63;
    const float4* srow = (const float4*)(s + (size_t)bh * S);
    const int4* mrow = (const int4*)(smask + b * S);

    float mx = -3.4e38f;
#pragma unroll
    for (int t = 0; t < 2; t++) {
        int i = tid + 256 * t;
        float4 v = srow[i]; int4 mk = mrow[i];
        if (mk.x) mx = fmaxf(mx, v.x);
        if (mk.y) mx = fmaxf(mx, v.y);
        if (mk.z) mx = fmaxf(mx, v.z);
        if (mk.w) mx = fmaxf(mx, v.w);
    }
    for (int off = 32; off > 0; off >>= 1) mx = fmaxf(mx, __shfl_down(mx, off));
    if (lane == 0) red[wave] = mx;
    __syncthreads();
    float gmax = fmaxf(fmaxf(red[0], red[1]), fmaxf(red[2], red[3]));
    __syncthreads();

    float sum = 0.f;
#pragma unroll
    for (int t = 0; t < 2; t++) {
        int i = tid + 256 * t;
        float4 v = srow[i]; int4 mk = mrow[i];
        if (mk.x) sum += expf(v.x - gmax);
        if (mk.y) sum += expf(v.y - gmax);
        if (mk.z) sum += expf(v.z - gmax);
        if (mk.w) sum += expf(v.w - gmax);
    }
    for (int off = 32; off > 0; off >>= 1) sum += __shfl_down(sum, off);
    if (lane == 0) red[wave] = sum;
    __syncthreads();
    if (tid == 0) { m[bh] = gmax; dsum[bh] = red[0] + red[1] + red[2] + red[3]; }
}

// ---- kD: fused head-mean weight + broadcast over query rows ---------------
// grid = B * (S/KC) * (S/QC) = 512 blocks. Each block computes its 1024-wide
// w chunk into LDS, then streams QC=16 output rows of it.
__global__ __launch_bounds__(256) void kD(const float* __restrict__ s,
                                          const int* __restrict__ smask,
                                          const float* __restrict__ m,
                                          const float* __restrict__ dsum,
                                          float* __restrict__ out) {
    __shared__ float wch[KC];  // 4 KB
    int blk = blockIdx.x;
    int b  = blk >> 8;                  // 256 blocks per batch
    int r  = blk & 255;
    int kc = r >> 7;                    // 0..1
    int q0 = (r & 127) * QC;
    int tid = threadIdx.x;

    // stats for this batch (wave-uniform scalar loads)
    float mh[NH], ih[NH];
#pragma unroll
    for (int h = 0; h < NH; h++) {
        mh[h] = m[b * NH + h];
        ih[h] = 1.0f / dsum[b * NH + h];
    }

    // compute w chunk: one float4 per thread
    {
        int k = kc * KC + tid * 4;
        int4 mk = *(const int4*)(smask + b * S + k);
        float4 val = make_float4(0.f, 0.f, 0.f, 0.f);
#pragma unroll
        for (int h = 0; h < NH; h++) {
            float4 sv = *(const float4*)(s + ((size_t)b * NH + h) * S + k);
            val.x += expf(sv.x - mh[h]) * ih[h];
            val.y += expf(sv.y - mh[h]) * ih[h];
            val.z += expf(sv.z - mh[h]) * ih[h];
            val.w += expf(sv.w - mh[h]) * ih[h];
        }
        const float inh = 1.0f / NH;
        val.x = mk.x ? val.x * inh : 0.f;
        val.y = mk.y ? val.y * inh : 0.f;
        val.z = mk.z ? val.z * inh : 0.f;
        val.w = mk.w ? val.w * inh : 0.f;
        ((float4*)wch)[tid] = val;
    }
    __syncthreads();

    // broadcast: QC rows, each row writes KC floats (256 float4)
    float4 v = ((float4*)wch)[tid];
#pragma unroll
    for (int qi = 0; qi < QC; qi++) {
        float4* dst = (float4*)(out + ((size_t)(b * S + q0 + qi)) * S + kc * KC);
        dst[tid] = v;
    }
}

extern "C" void kernel_launch(void* const* d_in, const int* in_sizes, int n_in,
                              void* d_out, int out_size, void* d_ws, size_t ws_size,
                              hipStream_t stream) {
    const float* h1    = (const float*)d_in[0];   // [B,S,H]
    const float* h2    = (const float*)d_in[1];   // [B,A,H]
    const int*   smask = (const int*)d_in[2];     // [B,S]
    const int*   amask = (const int*)d_in[3];     // [B,A]
    const float* Wq    = (const float*)d_in[4];   // [H,H]
    const float* Wk    = (const float*)d_in[5];   // [H,H]
    float* out = (float*)d_out;                   // [B,S,S]
    float* ws  = (float*)d_ws;

    float* weff = ws;            // B*NH*H = 32768 floats
    float* s    = ws + 32768;    // B*NH*S = 65536 floats
    float* m    = ws + 98304;    // 32
    float* dsum = ws + 98336;    // 32

    kQW<<<B * NH * CH, 256, 0, stream>>>(h2, amask, Wq, Wk, weff);
    kB <<<B * (S / KT) * 2, 256, 0, stream>>>(h1, weff, s);
    kS <<<B * NH, 256, 0, stream>>>(s, smask, m, dsum);
    kD <<<B * (S / KC) * (S / QC), 256, 0, stream>>>(s, smask, m, dsum, out);
}